// Round 6
// baseline (3725.009 us; speedup 1.0000x reference)
//
#include <hip/hip_runtime.h>
#include <math.h>

typedef _Float16 half8 __attribute__((ext_vector_type(8)));
typedef _Float16 half4 __attribute__((ext_vector_type(4)));
typedef float floatx4 __attribute__((ext_vector_type(4)));
typedef float floatx2 __attribute__((ext_vector_type(2)));
typedef unsigned int uintx4 __attribute__((ext_vector_type(4)));

#define NB 64
#define LQ 512
#define HD 1024
#define SENT 0x7E7E7E7Eu   // f16 NaN pair: tanh output can never equal this

__device__ inline half8 cvt2(const float4 a, const float4 b) {
  half8 h;
  h[0]=(_Float16)a.x; h[1]=(_Float16)a.y; h[2]=(_Float16)a.z; h[3]=(_Float16)a.w;
  h[4]=(_Float16)b.x; h[5]=(_Float16)b.y; h[6]=(_Float16)b.z; h[7]=(_Float16)b.w;
  return h;
}

// System-scope (sc0 sc1) accessors: bypass L1+L2, coherent at IF$.
__device__ inline floatx4 ld_sys16(const void* p) {
  floatx4 r;
  asm volatile("global_load_dwordx4 %0, %1, off sc0 sc1"
               : "=v"(r) : "v"(p) : "memory");
  return r;
}
// Two 8B stores publishing p0 (offset 0) and p1 (offset 512) in one asm.
__device__ inline void st_sys8x2(void* p, floatx2 a, floatx2 b) {
  asm volatile("global_store_dwordx2 %0, %1, off sc0 sc1\n\t"
               "global_store_dwordx2 %0, %2, off offset:512 sc0 sc1"
               :: "v"(p), "v"(a), "v"(b) : "memory");
}
__device__ inline void st_sys4(void* p, unsigned v) {
  asm volatile("global_store_dword %0, %1, off sc0 sc1"
               :: "v"(p), "v"(v) : "memory");
}
__device__ inline void vmcnt0() { asm volatile("s_waitcnt vmcnt(0)" ::: "memory"); }

// Fast tanh: 1 - 2/(e^{2x}+1). exp overflow/underflow saturate correctly.
__device__ inline float ftanh(float x) {
  float e = __expf(2.0f * x);
  return 1.0f - 2.0f / (e + 1.0f);
}

// ---------------------------------------------------------------------------
// GEMM1 (verified) + sentinel-init of the 4 h-slots (512 KB) each launch.
// ---------------------------------------------------------------------------
__global__ __launch_bounds__(256) void gemm1_kernel(
    const int* __restrict__ x, const float* __restrict__ emb,
    const float* __restrict__ Wxh, const float* __restrict__ bxh,
    const float* __restrict__ bhh, float* __restrict__ out,
    char* __restrict__ hb)
{
  // ---- sentinel-init: 2048 blocks x 64 lanes x 1 dword = 512 KB
  {
    const int bid = blockIdx.y * gridDim.x + blockIdx.x;
    if (threadIdx.x < 64)
      st_sys4((unsigned*)hb + (size_t)bid * 64 + threadIdx.x, SENT);
  }

  __shared__ alignas(16) _Float16 As[128][72];
  __shared__ alignas(16) _Float16 Bs[128][72];
  const int tid  = threadIdx.x;
  const int lane = tid & 63, wv = tid >> 6;
  const int wm = wv & 1, wn = wv >> 1;
  const int Mbase = blockIdx.x * 128;
  const int Nbase = blockIdx.y * 128;

  const int srow  = tid >> 1;
  const int shalf = tid & 1;
  const size_t erow = (size_t)x[Mbase + srow] * HD;
  const size_t brow = (size_t)(Nbase + srow) * HD;

  floatx4 acc[4][4];
#pragma unroll
  for (int i = 0; i < 4; i++)
#pragma unroll
    for (int j = 0; j < 4; j++) acc[i][j] = (floatx4)0.f;

  for (int c = 0; c < 16; ++c) {
    const int k0 = c * 64 + shalf * 32;
    const float4* ap = (const float4*)(emb + erow + k0);
    const float4* bp = (const float4*)(Wxh + brow + k0);
    float4 av[8], bv[8];
#pragma unroll
    for (int i = 0; i < 8; i++) { av[i] = ap[i]; bv[i] = bp[i]; }
    __syncthreads();
#pragma unroll
    for (int i = 0; i < 4; i++) {
      *(half8*)&As[srow][shalf*32 + i*8] = cvt2(av[2*i], av[2*i+1]);
      *(half8*)&Bs[srow][shalf*32 + i*8] = cvt2(bv[2*i], bv[2*i+1]);
    }
    __syncthreads();
#pragma unroll
    for (int s = 0; s < 2; ++s) {
      const int koff = s*32 + (lane >> 4) * 8;
      half8 af[4], bf[4];
#pragma unroll
      for (int i = 0; i < 4; i++) {
        af[i] = *(const half8*)&As[wm*64 + i*16 + (lane & 15)][koff];
        bf[i] = *(const half8*)&Bs[wn*64 + i*16 + (lane & 15)][koff];
      }
#pragma unroll
      for (int i = 0; i < 4; i++)
#pragma unroll
        for (int j = 0; j < 4; j++)
          acc[i][j] = __builtin_amdgcn_mfma_f32_16x16x32_f16(af[i], bf[j], acc[i][j], 0, 0, 0);
    }
  }
#pragma unroll
  for (int j = 0; j < 4; j++) {
    const int o = Nbase + wn*64 + j*16 + (lane & 15);
    const float bias = bxh[o] + bhh[o];
#pragma unroll
    for (int i = 0; i < 4; i++) {
      const int mb = Mbase + wm*64 + i*16 + ((lane >> 4) * 4);
#pragma unroll
      for (int r = 0; r < 4; r++)
        out[(size_t)(mb + r) * HD + o] = acc[i][j][r] + bias;
    }
  }
}

// ---------------------------------------------------------------------------
// RNN v5: flagless sentinel synchronization, system scope (IF$ coherent).
// h slots pre-filled with f16-NaN sentinel; the consumer's 32 coalesced 1 KB
// loads ARE the poll (reload only chunks still containing a sentinel dword).
// Producer publishes in consumer fragment order (2 coalesced 8B stores), no
// drain, no flags. 4-slot rotation; producer re-sentinels slot (t+2)&3
// (safe: any producer at step t implies all region-w readers of step t-2
// are done; same-wave same-address ordering via the step t+1 poll's vmcnt0).
// gemm1 re-initializes all slots each launch.
// ---------------------------------------------------------------------------
__global__ __launch_bounds__(256, 1) void rnn_kernel(
    const float* __restrict__ Whh, float* __restrict__ out,
    char* __restrict__ hb)
{
  __shared__ alignas(16) _Float16 Ws[32 * 1024];     // 64 KB W_hh slice (f16, swizzled)
  const int tid = threadIdx.x, lane = tid & 63, w = tid >> 6;
  const int j = blockIdx.x, obase = j * 32;
  const int col = lane & 15, quad = lane >> 4;

  // ---- stage W_hh slice fp32 -> f16, swizzled (unchanged, verified)
  {
    const int o = tid >> 3, t8 = tid & 7;
    const float* src = Whh + (size_t)(obase + o) * HD;
#pragma unroll
    for (int i = 0; i < 16; ++i) {
      const int c16 = t8 * 16 + i;
      float4 v0 = *(const float4*)(src + c16 * 8);
      float4 v1 = *(const float4*)(src + c16 * 8 + 4);
      *(half8*)&Ws[o * 1024 + ((c16 ^ (o & 7)) * 8)] = cvt2(v0, v1);
    }
  }
  __syncthreads();                                    // only barrier in the kernel

  const int n = 16 * w + col;                         // this lane's batch row
  float* outp = out + (size_t)n * LQ * HD + obase + quad * 4;
  char* hbw = hb + (size_t)w * 32768 + (size_t)lane * 16;   // consumer read base
  // producer publish base: byte (quad>>1)*256 + col*16 + (quad&1)*8 in chunk j
  char* pubb = hb + (size_t)w * 32768 + (size_t)j * 1024 +
               (size_t)((quad >> 1) * 256 + col * 16 + (quad & 1) * 8);
  const floatx2 sent2 = __builtin_bit_cast(floatx2, (unsigned long long)SENT << 32 | SENT);

  for (int t = 0; t < LQ; ++t) {
    // xh prefetch: own channels, contiguous float4
    const float* xp = outp + (size_t)t * HD;
    floatx4 xv0 = *(const floatx4*)xp;
    floatx4 xv1 = *(const floatx4*)(xp + 16);
    floatx4 acc0 = (floatx4)0.f, acc1 = (floatx4)0.f;

    if (t > 0) {
      // ---- sentinel-poll loads: h_{t-1} B-fragments, reload invalid chunks
      const char* blk = hbw + (size_t)((t - 1) & 3) * 131072;
      floatx4 hv[32];
      unsigned need = 0xFFFFFFFFu;
      int sweeps = 0;
      do {
#pragma unroll
        for (int c = 0; c < 32; ++c)
          if (need & (1u << c)) hv[c] = ld_sys16(blk + c * 1024);
        vmcnt0();
        __builtin_amdgcn_sched_barrier(0);
#pragma unroll
        for (int c = 0; c < 32; ++c)
          if (need & (1u << c)) {
            uintx4 u = __builtin_bit_cast(uintx4, hv[c]);
            if ((u[0] != SENT) & (u[1] != SENT) & (u[2] != SENT) & (u[3] != SENT))
              need &= ~(1u << c);
          }
      } while (need != 0 && ++sweeps < 4096);         // escape: wrong > hung

      // ---- 64 MFMA: 4 interleaved chains over K=1024
      floatx4 a0a = (floatx4)0.f, a1a = (floatx4)0.f;
      floatx4 a0b = (floatx4)0.f, a1b = (floatx4)0.f;
#pragma unroll
      for (int c = 0; c < 32; ++c) {
        const int sw = ((4 * c + quad) ^ (col & 7)) * 8;
        half8 b0 = *(const half8*)&Ws[col * 1024 + sw];
        half8 b1 = *(const half8*)&Ws[(16 + col) * 1024 + sw];
        half8 hf = __builtin_bit_cast(half8, hv[c]);
        if (c & 1) {
          a0b = __builtin_amdgcn_mfma_f32_16x16x32_f16(b0, hf, a0b, 0, 0, 0);
          a1b = __builtin_amdgcn_mfma_f32_16x16x32_f16(b1, hf, a1b, 0, 0, 0);
        } else {
          a0a = __builtin_amdgcn_mfma_f32_16x16x32_f16(b0, hf, a0a, 0, 0, 0);
          a1a = __builtin_amdgcn_mfma_f32_16x16x32_f16(b1, hf, a1a, 0, 0, 0);
        }
      }
      acc0 = a0a + a0b;
      acc1 = a1a + a1b;
    }

    // ---- h = tanh(acc + xh); channels contiguous per lane
    floatx4 h0, h1;
    half4 p0, p1;
#pragma unroll
    for (int r = 0; r < 4; ++r) {
      h0[r] = ftanh(acc0[r] + xv0[r]);
      h1[r] = ftanh(acc1[r] + xv1[r]);
      p0[r] = (_Float16)h0[r];
      p1[r] = (_Float16)h1[r];
    }

    // ---- publish in consumer fragment order: 2 coalesced 8B stores, NO drain
    st_sys8x2(pubb + (size_t)(t & 3) * 131072,
              __builtin_bit_cast(floatx2, p0), __builtin_bit_cast(floatx2, p1));

    // ---- re-sentinel slot for step t+2 (proof in header comment)
    st_sys8x2(pubb + (size_t)((t + 2) & 3) * 131072, sent2, sent2);

    // ---- out stores: off the critical path
    float* op = outp + (size_t)t * HD;
    *(floatx4*)op = h0;
    *(floatx4*)(op + 16) = h1;
  }
}

extern "C" void kernel_launch(void* const* d_in, const int* in_sizes, int n_in,
                              void* d_out, int out_size, void* d_ws, size_t ws_size,
                              hipStream_t stream) {
  const int*   x   = (const int*)d_in[0];
  const float* emb = (const float*)d_in[1];
  const float* Whh = (const float*)d_in[2];
  const float* bhh = (const float*)d_in[3];
  const float* Wxh = (const float*)d_in[4];
  const float* bxh = (const float*)d_in[5];
  float* out = (float*)d_out;

  char* hbuf = (char*)d_ws;                            // 4 x 128 KB fragment slots

  gemm1_kernel<<<dim3(256, 8), 256, 0, stream>>>(x, emb, Wxh, bxh, bhh, out, hbuf);
  rnn_kernel<<<dim3(32), 256, 0, stream>>>(Whh, out, hbuf);
}